// Round 2
// baseline (777.477 us; speedup 1.0000x reference)
//
#include <hip/hip_runtime.h>
#include <cstdint>
#include <cstddef>

#define T_ 4
#define N_ 512
#define C_ 256
#define V_ 25
#define H_ 8
#define XPAD 28   // padded V so per-k rows are 112B (16B-aligned) for float4 LDS reads

// ---------------- K0: transpose the 4 weight matrices: Wt[br][k][o] = w_br[o][k] ----
__global__ void k0_transpose(const float* __restrict__ wq, const float* __restrict__ wk,
                             const float* __restrict__ wv, const float* __restrict__ wp,
                             float* __restrict__ Wt) {
  __shared__ float tile[64][65];
  const int tr = blockIdx.x, tc = blockIdx.y, br = blockIdx.z;
  const float* w = (br == 0) ? wq : (br == 1) ? wk : (br == 2) ? wv : wp;
  const int lane = threadIdx.x & 63, grp = threadIdx.x >> 6;
#pragma unroll
  for (int j = 0; j < 16; ++j) {
    int r = grp * 16 + j;
    tile[r][lane] = w[(tr * 64 + r) * 256 + tc * 64 + lane];
  }
  __syncthreads();
#pragma unroll
  for (int j = 0; j < 16; ++j) {
    int kk = grp * 16 + j;
    Wt[((size_t)br << 16) + (size_t)(tc * 64 + kk) * 256 + tr * 64 + lane] = tile[lane][kk];
  }
}

// ---------------- K1: fused qkv conv + BN + LIF -> spike bitmasks --------------------
// block = one n (512 blocks x 512 threads). Waves: wid = (t, g); lane = output row a.
// masks layout: [t][n][br][h][v] uint32 (bits over d = c&31)
__launch_bounds__(512, 1)
__global__ void k1_qkv(const float* __restrict__ x, const float* __restrict__ Wt,
                       const float* __restrict__ qg, const float* __restrict__ qb,
                       const float* __restrict__ qm, const float* __restrict__ qvar,
                       const float* __restrict__ kg, const float* __restrict__ kb,
                       const float* __restrict__ km, const float* __restrict__ kvar,
                       const float* __restrict__ vg, const float* __restrict__ vb,
                       const float* __restrict__ vm, const float* __restrict__ vvar,
                       uint32_t* __restrict__ masks) {
  __shared__ __align__(16) float Xs[T_ * C_ * XPAD];  // 114688 B
  __shared__ __align__(16) float Ws[128 * 64];        // 32768 B; aliased as cur[4][64][25]
  const int n = blockIdx.x;
  const int tid = threadIdx.x;
  const int lane = tid & 63;
  const int wid = tid >> 6;
  const int t = wid & 3;
  const int voff = (wid >> 2) * 12;             // v range: [voff, voff+13), overlap at v=12 benign

  // stage x[t,n,:,:] into padded LDS
  for (int idx = tid; idx < T_ * C_ * V_; idx += 512) {
    int tt = idx / (C_ * V_);
    int r = idx - tt * (C_ * V_);
    int k = r / V_;
    int v = r - k * V_;
    Xs[(tt * C_ + k) * XPAD + v] = x[(size_t)(tt * N_ + n) * (C_ * V_) + r];
  }

  for (int chunk = 0; chunk < 12; ++chunk) {
    const int br = chunk >> 2;
    const int rowloc = (chunk & 3) * 64;
    const float* wtb = Wt + ((size_t)br << 16) + rowloc;
    float acc[13];
#pragma unroll
    for (int i = 0; i < 13; ++i) acc[i] = 0.0f;

#pragma unroll
    for (int kh = 0; kh < 2; ++kh) {
      __syncthreads();  // covers Xs staging (first iter) / cur-phase & prev tile reads
      {
        int kk = tid >> 2;
        int aq = (tid & 3) * 16;
        const float4* s4 = (const float4*)(wtb + (size_t)(kh * 128 + kk) * 256 + aq);
        float4* d4 = (float4*)&Ws[kk * 64 + aq];
        d4[0] = s4[0]; d4[1] = s4[1]; d4[2] = s4[2]; d4[3] = s4[3];
      }
      __syncthreads();
      const float* xrow = &Xs[(t * C_ + kh * 128) * XPAD + voff];
#pragma unroll 4
      for (int kk = 0; kk < 128; ++kk) {
        float w = Ws[kk * 64 + lane];
        const float* xp = xrow + kk * XPAD;
        float4 x0 = *(const float4*)(xp);
        float4 x1 = *(const float4*)(xp + 4);
        float4 x2 = *(const float4*)(xp + 8);
        float xsc = xp[12];
        acc[0]  = fmaf(w, x0.x, acc[0]);
        acc[1]  = fmaf(w, x0.y, acc[1]);
        acc[2]  = fmaf(w, x0.z, acc[2]);
        acc[3]  = fmaf(w, x0.w, acc[3]);
        acc[4]  = fmaf(w, x1.x, acc[4]);
        acc[5]  = fmaf(w, x1.y, acc[5]);
        acc[6]  = fmaf(w, x1.z, acc[6]);
        acc[7]  = fmaf(w, x1.w, acc[7]);
        acc[8]  = fmaf(w, x2.x, acc[8]);
        acc[9]  = fmaf(w, x2.y, acc[9]);
        acc[10] = fmaf(w, x2.z, acc[10]);
        acc[11] = fmaf(w, x2.w, acc[11]);
        acc[12] = fmaf(w, xsc, acc[12]);
      }
    }

    // BN affine (fold gamma/beta/mean/var)
    const int c = rowloc + lane;
    float ga, be, mu, va;
    if (br == 0)      { ga = qg[c]; be = qb[c]; mu = qm[c]; va = qvar[c]; }
    else if (br == 1) { ga = kg[c]; be = kb[c]; mu = km[c]; va = kvar[c]; }
    else              { ga = vg[c]; be = vb[c]; mu = vm[c]; va = vvar[c]; }
    float sc = ga / sqrtf(va + 1e-5f);
    float bi = be - mu * sc;

    __syncthreads();  // all waves done reading Ws tile before aliasing it as cur
#pragma unroll
    for (int i = 0; i < 13; ++i)
      Ws[(t * 64 + lane) * 25 + voff + i] = fmaf(acc[i], sc, bi);
    __syncthreads();

    // LIF over t (v_th = 1.0), pack spikes via ballot: bit d = lane&31
    const int h0 = (chunk & 3) * 2;
    for (int vv = wid; vv < V_; vv += 8) {
      float st = 0.0f;
#pragma unroll
      for (int tt = 0; tt < 4; ++tt) {
        float cu = Ws[(tt * 64 + lane) * 25 + vv];
        st += (cu - st) * 0.5f;
        bool s = (st >= 1.0f);
        if (s) st = 0.0f;
        unsigned long long b = __ballot(s);
        if (lane == 0)
          masks[((((size_t)tt * N_ + n) * 3 + br) * H_ + h0) * V_ + vv] = (uint32_t)b;
        else if (lane == 32)
          masks[((((size_t)tt * N_ + n) * 3 + br) * H_ + h0 + 1) * V_ + vv] = (uint32_t)(b >> 32);
      }
    }
    __syncthreads();  // LIF reads done before next chunk overwrites Ws
  }
}

// ---------------- K2: binary attention (popcount) + attn_lif -> mask2 ----------------
// block = (n, h), 64 threads. lane -> (v parity, d). mask2 layout: [t][n][v][h] uint32 over d.
__launch_bounds__(64)
__global__ void k2_attn(const uint32_t* __restrict__ masks, uint32_t* __restrict__ mask2) {
  __shared__ uint32_t qs[T_][V_], ks_[T_][V_], vs[T_][V_];
  const int n = blockIdx.x >> 3;
  const int h = blockIdx.x & 7;
  const int l = threadIdx.x;
  for (int i = l; i < T_ * 3 * V_; i += 64) {
    int t = i / (3 * V_);
    int r = i - t * (3 * V_);
    int br = r / V_;
    int v = r - br * V_;
    uint32_t w = masks[(((size_t)t * N_ + n) * 3 + br) * (H_ * V_) + h * V_ + v];
    if (br == 0) qs[t][v] = w;
    else if (br == 1) ks_[t][v] = w;
    else vs[t][v] = w;
  }
  __syncthreads();
  const int hi = l >> 5, d = l & 31;
  for (int vv = 0; vv < 13; ++vv) {
    int v = vv * 2 + hi;
    bool valid = (v < V_);
    int vc = valid ? v : 0;
    float st = 0.0f;
#pragma unroll
    for (int t = 0; t < 4; ++t) {
      int y = 0;
      uint32_t qmw = qs[t][vc];
#pragma unroll
      for (int w = 0; w < V_; ++w) {
        int a = __popc(qmw & ks_[t][w]);
        y += a * (int)((vs[t][w] >> d) & 1u);
      }
      // y exact integer; 0.125*y exact dyadic -> attn_lif is bit-exact
      float yf = 0.125f * (float)y;
      st += (yf - st) * 0.5f;
      bool s = valid && (st >= 0.5f);
      if (st >= 0.5f) st = 0.0f;
      unsigned long long b = __ballot(s);
      if (valid && (l == 0 || l == 32)) {
        uint32_t wd = (l == 0) ? (uint32_t)b : (uint32_t)(b >> 32);
        mask2[(((size_t)t * N_ + n) * V_ + v) * H_ + h] = wd;
      }
    }
  }
}

// ---------------- K3: proj conv + bias + BN + LIF + residual ------------------------
__launch_bounds__(512, 1)
__global__ void k3_proj(const float* __restrict__ x, const float* __restrict__ Wt,
                        const uint32_t* __restrict__ mask2, const float* __restrict__ bp,
                        const float* __restrict__ pg, const float* __restrict__ pb,
                        const float* __restrict__ pm, const float* __restrict__ pvar,
                        float* __restrict__ out) {
  __shared__ __align__(16) float Xs[T_ * C_ * XPAD];
  __shared__ __align__(16) float Ws[128 * 64];
  const int n = blockIdx.x;
  const int tid = threadIdx.x;
  const int lane = tid & 63;
  const int wid = tid >> 6;
  const int t = wid & 3;
  const int voff = (wid >> 2) * 12;

  // stage mask2[:, n, :, :] then expand spikes to 0/1 floats in padded LDS
  uint32_t* m2s = (uint32_t*)Ws;  // 800 words
  for (int i = tid; i < T_ * V_ * H_; i += 512) {
    int tt = i / 200;
    int r = i - tt * 200;
    m2s[i] = mask2[(size_t)tt * (N_ * 200) + (size_t)n * 200 + r];
  }
  __syncthreads();
  for (int idx = tid; idx < T_ * C_ * V_; idx += 512) {
    int tt = idx / (C_ * V_);
    int r = idx - tt * (C_ * V_);
    int k = r / V_;
    int v = r - k * V_;
    uint32_t wbits = m2s[tt * 200 + v * 8 + (k >> 5)];
    Xs[(tt * C_ + k) * XPAD + v] = (float)((wbits >> (k & 31)) & 1u);
  }

  const float* wtb0 = Wt + ((size_t)3 << 16);
  for (int chunk = 0; chunk < 4; ++chunk) {
    const int rowloc = chunk * 64;
    const float* wtb = wtb0 + rowloc;
    float acc[13];
#pragma unroll
    for (int i = 0; i < 13; ++i) acc[i] = 0.0f;

#pragma unroll
    for (int kh = 0; kh < 2; ++kh) {
      __syncthreads();  // covers Xs expansion (first iter) / prior phases
      {
        int kk = tid >> 2;
        int aq = (tid & 3) * 16;
        const float4* s4 = (const float4*)(wtb + (size_t)(kh * 128 + kk) * 256 + aq);
        float4* d4 = (float4*)&Ws[kk * 64 + aq];
        d4[0] = s4[0]; d4[1] = s4[1]; d4[2] = s4[2]; d4[3] = s4[3];
      }
      __syncthreads();
      const float* xrow = &Xs[(t * C_ + kh * 128) * XPAD + voff];
#pragma unroll 4
      for (int kk = 0; kk < 128; ++kk) {
        float w = Ws[kk * 64 + lane];
        const float* xp = xrow + kk * XPAD;
        float4 x0 = *(const float4*)(xp);
        float4 x1 = *(const float4*)(xp + 4);
        float4 x2 = *(const float4*)(xp + 8);
        float xsc = xp[12];
        acc[0]  = fmaf(w, x0.x, acc[0]);
        acc[1]  = fmaf(w, x0.y, acc[1]);
        acc[2]  = fmaf(w, x0.z, acc[2]);
        acc[3]  = fmaf(w, x0.w, acc[3]);
        acc[4]  = fmaf(w, x1.x, acc[4]);
        acc[5]  = fmaf(w, x1.y, acc[5]);
        acc[6]  = fmaf(w, x1.z, acc[6]);
        acc[7]  = fmaf(w, x1.w, acc[7]);
        acc[8]  = fmaf(w, x2.x, acc[8]);
        acc[9]  = fmaf(w, x2.y, acc[9]);
        acc[10] = fmaf(w, x2.z, acc[10]);
        acc[11] = fmaf(w, x2.w, acc[11]);
        acc[12] = fmaf(w, xsc, acc[12]);
      }
    }

    // bias + BN folded: y = conv*sc + ((bp-pm)*sc + pb)
    const int c = rowloc + lane;
    float sc = pg[c] / sqrtf(pvar[c] + 1e-5f);
    float bi = fmaf(bp[c] - pm[c], sc, pb[c]);

    __syncthreads();
#pragma unroll
    for (int i = 0; i < 13; ++i)
      Ws[(t * 64 + lane) * 25 + voff + i] = fmaf(acc[i], sc, bi);
    __syncthreads();

    // LIF (v_th = 1.0), write spike back in place
    for (int vv = wid; vv < V_; vv += 8) {
      float st = 0.0f;
#pragma unroll
      for (int tt = 0; tt < 4; ++tt) {
        float cu = Ws[(tt * 64 + lane) * 25 + vv];
        st += (cu - st) * 0.5f;
        float s = (st >= 1.0f) ? 1.0f : 0.0f;
        if (st >= 1.0f) st = 0.0f;
        Ws[(tt * 64 + lane) * 25 + vv] = s;
      }
    }
    __syncthreads();

    // coalesced residual add + store
    for (int ii = tid; ii < 4 * 1600; ii += 512) {
      int tt = ii / 1600;
      int idx2 = ii - tt * 1600;
      size_t go = (size_t)(tt * N_ + n) * (C_ * V_) + (size_t)rowloc * V_ + idx2;
      out[go] = Ws[tt * 1600 + idx2] + x[go];
    }
    // next chunk's kh-top barrier protects Ws reuse
  }
}

extern "C" void kernel_launch(void* const* d_in, const int* in_sizes, int n_in,
                              void* d_out, int out_size, void* d_ws, size_t ws_size,
                              hipStream_t stream) {
  const float* x    = (const float*)d_in[0];
  const float* wq   = (const float*)d_in[1];
  const float* wk   = (const float*)d_in[2];
  const float* wv   = (const float*)d_in[3];
  const float* wp   = (const float*)d_in[4];
  const float* bp   = (const float*)d_in[5];
  const float* qg   = (const float*)d_in[6];
  const float* qb   = (const float*)d_in[7];
  const float* qm   = (const float*)d_in[8];
  const float* qvar = (const float*)d_in[9];
  const float* kg   = (const float*)d_in[10];
  const float* kb   = (const float*)d_in[11];
  const float* km   = (const float*)d_in[12];
  const float* kvar = (const float*)d_in[13];
  const float* vg   = (const float*)d_in[14];
  const float* vb   = (const float*)d_in[15];
  const float* vm   = (const float*)d_in[16];
  const float* vvar = (const float*)d_in[17];
  const float* pg   = (const float*)d_in[18];
  const float* pb   = (const float*)d_in[19];
  const float* pm   = (const float*)d_in[20];
  const float* pvar = (const float*)d_in[21];

  float* Wt = (float*)d_ws;
  uint32_t* masks = (uint32_t*)d_ws + 262144;   // 4*512*3*8*25 = 1,228,800 words
  uint32_t* mask2 = masks + 1228800;            // 4*512*25*8 = 409,600 words

  k0_transpose<<<dim3(4, 4, 4), 256, 0, stream>>>(wq, wk, wv, wp, Wt);
  k1_qkv<<<512, 512, 0, stream>>>(x, Wt, qg, qb, qm, qvar, kg, kb, km, kvar,
                                  vg, vb, vm, vvar, masks);
  k2_attn<<<4096, 64, 0, stream>>>(masks, mask2);
  k3_proj<<<512, 512, 0, stream>>>(x, Wt, mask2, bp, pg, pb, pm, pvar, (float*)d_out);
}

// Round 3
// 415.602 us; speedup vs baseline: 1.8707x; 1.8707x over previous
//
#include <hip/hip_runtime.h>
#include <cstdint>
#include <cstddef>

#define T_ 4
#define N_ 512
#define C_ 256
#define V_ 25
#define H_ 8

typedef _Float16 half8_t __attribute__((ext_vector_type(8)));
typedef float f32x16 __attribute__((ext_vector_type(16)));

__device__ __forceinline__ f32x16 mfma16(half8_t a, half8_t b, f32x16 c) {
  return __builtin_amdgcn_mfma_f32_32x32x16_f16(a, b, c, 0, 0, 0);
}

__device__ __forceinline__ uint32_t pack2h(_Float16 a, _Float16 b) {
  union { _Float16 h[2]; uint32_t u; } u_;
  u_.h[0] = a; u_.h[1] = b;
  return u_.u;
}

// ---- KW: split BN-scaled weights into fp16 hi/lo: rows 0..767 = q,k,v; 768..1023 = proj
__global__ void kw_split(const float* __restrict__ wq, const float* __restrict__ wk,
                         const float* __restrict__ wv, const float* __restrict__ wp,
                         const float* __restrict__ qg, const float* __restrict__ qvar,
                         const float* __restrict__ kg, const float* __restrict__ kvar,
                         const float* __restrict__ vg, const float* __restrict__ vvar,
                         const float* __restrict__ pg, const float* __restrict__ pvar,
                         _Float16* __restrict__ W0, _Float16* __restrict__ W1) {
  int idx = blockIdx.x * 512 + threadIdx.x;          // < 262144
  int mat = idx >> 16, off = idx & 65535, co = off >> 8;
  const float* w  = mat == 0 ? wq : mat == 1 ? wk : mat == 2 ? wv : wp;
  const float* g  = mat == 0 ? qg : mat == 1 ? kg : mat == 2 ? vg : pg;
  const float* va = mat == 0 ? qvar : mat == 1 ? kvar : mat == 2 ? vvar : pvar;
  float sc = g[co] / sqrtf(va[co] + 1e-5f);
  float wv_ = w[off] * sc;
  _Float16 a = (_Float16)wv_;
  W0[idx] = a;
  W1[idx] = (_Float16)(wv_ - (float)a);
}

// ---- K1: fused qkv conv(BN-folded, fp16-split MFMA) + LIF -> spike bitmasks ----
// block = n, 512 threads = 8 waves (2 rowgroups x 4 colgroups). Panel cols: col = t*32 + v.
__launch_bounds__(512, 2)
__global__ void k1_mfma(const float* __restrict__ x,
                        const _Float16* __restrict__ W0, const _Float16* __restrict__ W1,
                        const float* __restrict__ qg, const float* __restrict__ qb,
                        const float* __restrict__ qm, const float* __restrict__ qvar,
                        const float* __restrict__ kg, const float* __restrict__ kb,
                        const float* __restrict__ km, const float* __restrict__ kvar,
                        const float* __restrict__ vg, const float* __restrict__ vb,
                        const float* __restrict__ vm, const float* __restrict__ vvar,
                        uint32_t* __restrict__ masks) {
  __shared__ __align__(16) _Float16 X0s[128 * 256];  // 64 KB, swizzled [col][k]
  __shared__ __align__(16) _Float16 X1s[128 * 256];  // 64 KB
  __shared__ float Ms[64 * 101];                     // 25856 B membrane buffer
  __shared__ float bic[128];
  const int n = blockIdx.x, tid = threadIdx.x;
  const int lane = tid & 63, wid = tid >> 6;
  const int rg = wid >> 2, cg = wid & 3;
  const int lr = lane & 31, lkg = lane >> 5;

  // stage x -> fp16-split swizzled panels (k-pairs packed as u32)
  for (int i = tid; i < 12800; i += 512) {
    int t = i / 3200, r = i - t * 3200;
    int cp = r / 25, v = r - cp * 25;
    int c = cp * 2;
    size_t gb = (size_t)(t * N_ + n) * 6400 + (size_t)c * 25 + v;
    float xa = x[gb], xb = x[gb + 25];
    _Float16 a0 = (_Float16)xa, b0 = (_Float16)xb;
    _Float16 a1 = (_Float16)(xa - (float)a0), b1 = (_Float16)(xb - (float)b0);
    int col = t * 32 + v;
    int bo = (col << 9) + ((c << 1) ^ ((col & 7) << 4));
    *(uint32_t*)((char*)X0s + bo) = pack2h(a0, b0);
    *(uint32_t*)((char*)X1s + bo) = pack2h(a1, b1);
  }
  // zero the pad cols v=25..31
  for (int i = tid; i < 3584; i += 512) {
    int t = i / 896, r = i - t * 896;
    int vv = r / 128, cp = r - vv * 128;
    int col = t * 32 + 25 + vv;
    int bo = (col << 9) + ((cp << 2) ^ ((col & 7) << 4));
    *(uint32_t*)((char*)X0s + bo) = 0u;
    *(uint32_t*)((char*)X1s + bo) = 0u;
  }
  __syncthreads();

  for (int chunk = 0; chunk < 6; ++chunk) {
    const int br = chunk >> 1;
    const int cbase = (chunk & 1) * 128;
    if (tid < 128) {
      int c = cbase + tid;
      const float* g  = br == 0 ? qg : br == 1 ? kg : vg;
      const float* be = br == 0 ? qb : br == 1 ? kb : vb;
      const float* mu = br == 0 ? qm : br == 1 ? km : vm;
      const float* va = br == 0 ? qvar : br == 1 ? kvar : vvar;
      float sc = g[c] / sqrtf(va[c] + 1e-5f);
      bic[tid] = be[c] - mu[c] * sc;
    }

    f32x16 acc0 = {}, acc1 = {};
    const size_t wr0 = (size_t)(br * 256 + cbase + rg * 64 + lr) * 256;
    const size_t wr1 = wr0 + (size_t)32 * 256;
    const int colb = (cg * 32 + lr) << 9;
    const int bxor = ((cg * 32 + lr) & 7) << 4;
    half8_t A00[2], A01[2], A10[2], A11[2], Bf0[2], Bf1[2];
#define K1LOAD(kt, s) do { \
      int ko = (kt) * 16 + lkg * 8; \
      A00[s] = *(const half8_t*)(W0 + wr0 + ko); \
      A01[s] = *(const half8_t*)(W0 + wr1 + ko); \
      A10[s] = *(const half8_t*)(W1 + wr0 + ko); \
      A11[s] = *(const half8_t*)(W1 + wr1 + ko); \
      int kb = ((kt) * 32 + lkg * 16) ^ bxor; \
      Bf0[s] = *(const half8_t*)((const char*)X0s + colb + kb); \
      Bf1[s] = *(const half8_t*)((const char*)X1s + colb + kb); \
    } while (0)
    K1LOAD(0, 0);
#pragma unroll
    for (int kt = 0; kt < 16; ++kt) {
      int cur = kt & 1, nxt = cur ^ 1;
      if (kt < 15) K1LOAD(kt + 1, nxt);
      acc0 = mfma16(A00[cur], Bf0[cur], acc0);
      acc1 = mfma16(A01[cur], Bf0[cur], acc1);
      acc0 = mfma16(A00[cur], Bf1[cur], acc0);
      acc1 = mfma16(A01[cur], Bf1[cur], acc1);
      acc0 = mfma16(A10[cur], Bf0[cur], acc0);
      acc1 = mfma16(A11[cur], Bf0[cur], acc1);
    }
#undef K1LOAD

    for (int p = 0; p < 2; ++p) {
      __syncthreads();  // Ms free (prev phase/chunk done) + bic ready
      if (rg == p && lr < 25) {
#pragma unroll
        for (int rr = 0; rr < 16; ++rr) {
          int rowc = (rr & 3) + 8 * (rr >> 2) + 4 * lkg;
          Ms[rowc * 101 + cg * 25 + lr] = acc0[rr] + bic[p * 64 + rowc];
          Ms[(32 + rowc) * 101 + cg * 25 + lr] = acc1[rr] + bic[p * 64 + 32 + rowc];
        }
      }
      __syncthreads();
      // LIF over t + ballot pack: tasks = (h_loc 0..1) x (v 0..24), lane d = channel bit
      const int d = lane & 31, sub = lane >> 5;
      for (int it = 0; it < 4; ++it) {
        int ti = it * 16 + wid * 2 + sub;
        bool valid = ti < 50;
        int hl = valid ? ti / 25 : 0;
        int v = valid ? ti - hl * 25 : 0;
        int row = hl * 32 + d;
        float st = 0.0f;
#pragma unroll
        for (int t = 0; t < 4; ++t) {
          float cu = Ms[row * 101 + t * 25 + v];
          st += (cu - st) * 0.5f;
          bool s = valid && (st >= 1.0f);
          if (st >= 1.0f) st = 0.0f;
          unsigned long long b = __ballot(s);
          if (valid && (lane == 0 || lane == 32)) {
            uint32_t wd = (lane == 0) ? (uint32_t)b : (uint32_t)(b >> 32);
            int hg = (chunk & 1) * 4 + p * 2 + hl;
            masks[((((size_t)t * N_ + n) * 3 + br) * H_ + hg) * V_ + v] = wd;
          }
        }
      }
    }
  }
}

// ---- K2: binary attention (popcount) + attn_lif -> mask2 (exact dyadic) ----
__launch_bounds__(64)
__global__ void k2_attn(const uint32_t* __restrict__ masks, uint32_t* __restrict__ mask2) {
  __shared__ uint32_t qs[T_][V_], ks_[T_][V_], vs[T_][V_];
  const int n = blockIdx.x >> 3;
  const int h = blockIdx.x & 7;
  const int l = threadIdx.x;
  for (int i = l; i < T_ * 3 * V_; i += 64) {
    int t = i / (3 * V_);
    int r = i - t * (3 * V_);
    int br = r / V_;
    int v = r - br * V_;
    uint32_t w = masks[(((size_t)t * N_ + n) * 3 + br) * (H_ * V_) + h * V_ + v];
    if (br == 0) qs[t][v] = w;
    else if (br == 1) ks_[t][v] = w;
    else vs[t][v] = w;
  }
  __syncthreads();
  const int hi = l >> 5, d = l & 31;
  for (int vv = 0; vv < 13; ++vv) {
    int v = vv * 2 + hi;
    bool valid = (v < V_);
    int vc = valid ? v : 0;
    float st = 0.0f;
#pragma unroll
    for (int t = 0; t < 4; ++t) {
      int y = 0;
      uint32_t qmw = qs[t][vc];
#pragma unroll
      for (int w = 0; w < V_; ++w) {
        int a = __popc(qmw & ks_[t][w]);
        y += a * (int)((vs[t][w] >> d) & 1u);
      }
      float yf = 0.125f * (float)y;
      st += (yf - st) * 0.5f;
      bool s = valid && (st >= 0.5f);
      if (st >= 0.5f) st = 0.0f;
      unsigned long long b = __ballot(s);
      if (valid && (l == 0 || l == 32)) {
        uint32_t wd = (l == 0) ? (uint32_t)b : (uint32_t)(b >> 32);
        mask2[(((size_t)t * N_ + n) * V_ + v) * H_ + h] = wd;
      }
    }
  }
}

// ---- K3: proj conv (binary input, fp16-split MFMA) + bias/BN + LIF + residual ----
__launch_bounds__(512, 2)
__global__ void k3_mfma(const float* __restrict__ x,
                        const _Float16* __restrict__ W0, const _Float16* __restrict__ W1,
                        const uint32_t* __restrict__ mask2, const float* __restrict__ bp,
                        const float* __restrict__ pg, const float* __restrict__ pb,
                        const float* __restrict__ pm, const float* __restrict__ pvar,
                        float* __restrict__ out) {
  __shared__ __align__(16) _Float16 XBs[128 * 256];  // 64 KB swizzled binary panel
  __shared__ float Ms[64 * 101];
  __shared__ float bic[128];
  __shared__ uint32_t m2s[800];
  const int n = blockIdx.x, tid = threadIdx.x;
  const int lane = tid & 63, wid = tid >> 6;
  const int rg = wid >> 2, cg = wid & 3;
  const int lr = lane & 31, lkg = lane >> 5;

  for (int i = tid; i < 800; i += 512) {
    int t = i / 200, r = i - t * 200;
    m2s[i] = mask2[(size_t)(t * N_ + n) * 200 + r];
  }
  __syncthreads();
  for (int i = tid; i < 12800; i += 512) {
    int t = i / 3200, r = i - t * 3200;
    int cp = r / 25, v = r - cp * 25;
    int c = cp * 2;
    uint32_t wbits = m2s[t * 200 + v * 8 + (c >> 5)];
    uint32_t lo = ((wbits >> (c & 31)) & 1u) ? 0x3C00u : 0u;
    uint32_t hi = ((wbits >> ((c + 1) & 31)) & 1u) ? 0x3C00u : 0u;
    int col = t * 32 + v;
    int bo = (col << 9) + ((c << 1) ^ ((col & 7) << 4));
    *(uint32_t*)((char*)XBs + bo) = lo | (hi << 16);
  }
  for (int i = tid; i < 3584; i += 512) {
    int t = i / 896, r = i - t * 896;
    int vv = r / 128, cp = r - vv * 128;
    int col = t * 32 + 25 + vv;
    int bo = (col << 9) + ((cp << 2) ^ ((col & 7) << 4));
    *(uint32_t*)((char*)XBs + bo) = 0u;
  }
  __syncthreads();

  for (int chunk = 0; chunk < 2; ++chunk) {
    if (tid < 128) {
      int c = chunk * 128 + tid;
      float sc = pg[c] / sqrtf(pvar[c] + 1e-5f);
      bic[tid] = fmaf(bp[c] - pm[c], sc, pb[c]);
    }
    f32x16 acc0 = {}, acc1 = {};
    const size_t wr0 = (size_t)(768 + chunk * 128 + rg * 64 + lr) * 256;
    const size_t wr1 = wr0 + (size_t)32 * 256;
    const int colb = (cg * 32 + lr) << 9;
    const int bxor = ((cg * 32 + lr) & 7) << 4;
    half8_t A0[2], A1[2], B0_[2], B1_[2];
#define K3LOAD(kt, s) do { \
      int ko = (kt) * 16 + lkg * 8; \
      A0[s] = *(const half8_t*)(W0 + wr0 + ko); \
      A1[s] = *(const half8_t*)(W0 + wr1 + ko); \
      B0_[s] = *(const half8_t*)(W1 + wr0 + ko); \
      B1_[s] = *(const half8_t*)(W1 + wr1 + ko); \
      Bf[s] = *(const half8_t*)((const char*)XBs + colb + (((kt) * 32 + lkg * 16) ^ bxor)); \
    } while (0)
    half8_t Bf[2];
    K3LOAD(0, 0);
#pragma unroll
    for (int kt = 0; kt < 16; ++kt) {
      int cur = kt & 1, nxt = cur ^ 1;
      if (kt < 15) K3LOAD(kt + 1, nxt);
      acc0 = mfma16(A0[cur], Bf[cur], acc0);
      acc1 = mfma16(A1[cur], Bf[cur], acc1);
      acc0 = mfma16(B0_[cur], Bf[cur], acc0);
      acc1 = mfma16(B1_[cur], Bf[cur], acc1);
    }
#undef K3LOAD

    for (int p = 0; p < 2; ++p) {
      __syncthreads();
      if (rg == p && lr < 25) {
#pragma unroll
        for (int rr = 0; rr < 16; ++rr) {
          int rowc = (rr & 3) + 8 * (rr >> 2) + 4 * lkg;
          Ms[rowc * 101 + cg * 25 + lr] = acc0[rr] + bic[p * 64 + rowc];
          Ms[(32 + rowc) * 101 + cg * 25 + lr] = acc1[rr] + bic[p * 64 + 32 + rowc];
        }
      }
      __syncthreads();
      const int d = lane & 31, sub = lane >> 5;
      for (int it = 0; it < 4; ++it) {
        int ti = it * 16 + wid * 2 + sub;
        if (ti < 50) {
          int hl = ti / 25, v = ti - hl * 25;
          int row = hl * 32 + d;
          float st = 0.0f;
#pragma unroll
          for (int t = 0; t < 4; ++t) {
            float cu = Ms[row * 101 + t * 25 + v];
            st += (cu - st) * 0.5f;
            float s = (st >= 1.0f) ? 1.0f : 0.0f;
            if (st >= 1.0f) st = 0.0f;
            Ms[row * 101 + t * 25 + v] = s;
          }
        }
      }
      __syncthreads();
      for (int ii = tid; ii < 6400; ii += 512) {
        int t = ii / 1600, r2 = ii - t * 1600;
        int cl = r2 / 25, v = r2 - cl * 25;
        size_t go = (size_t)(t * N_ + n) * 6400 + (size_t)(chunk * 128 + p * 64 + cl) * 25 + v;
        out[go] = Ms[cl * 101 + t * 25 + v] + x[go];
      }
    }
  }
}

extern "C" void kernel_launch(void* const* d_in, const int* in_sizes, int n_in,
                              void* d_out, int out_size, void* d_ws, size_t ws_size,
                              hipStream_t stream) {
  const float* x    = (const float*)d_in[0];
  const float* wq   = (const float*)d_in[1];
  const float* wk   = (const float*)d_in[2];
  const float* wv   = (const float*)d_in[3];
  const float* wp   = (const float*)d_in[4];
  const float* bp   = (const float*)d_in[5];
  const float* qg   = (const float*)d_in[6];
  const float* qb   = (const float*)d_in[7];
  const float* qm   = (const float*)d_in[8];
  const float* qvar = (const float*)d_in[9];
  const float* kg   = (const float*)d_in[10];
  const float* kb   = (const float*)d_in[11];
  const float* km   = (const float*)d_in[12];
  const float* kvar = (const float*)d_in[13];
  const float* vg   = (const float*)d_in[14];
  const float* vb   = (const float*)d_in[15];
  const float* vm   = (const float*)d_in[16];
  const float* vvar = (const float*)d_in[17];
  const float* pg   = (const float*)d_in[18];
  const float* pb   = (const float*)d_in[19];
  const float* pm   = (const float*)d_in[20];
  const float* pvar = (const float*)d_in[21];

  _Float16* W0 = (_Float16*)d_ws;                    // [1024][256]
  _Float16* W1 = W0 + 262144;
  uint32_t* masks = (uint32_t*)d_ws + 262144;        // after 1 MB of fp16 weights
  uint32_t* mask2 = masks + 1228800;

  kw_split<<<512, 512, 0, stream>>>(wq, wk, wv, wp, qg, qvar, kg, kvar,
                                    vg, vvar, pg, pvar, W0, W1);
  k1_mfma<<<512, 512, 0, stream>>>(x, W0, W1, qg, qb, qm, qvar, kg, kb, km, kvar,
                                   vg, vb, vm, vvar, masks);
  k2_attn<<<4096, 64, 0, stream>>>(masks, mask2);
  k3_mfma<<<512, 512, 0, stream>>>(x, W0, W1, mask2, bp, pg, pb, pm, pvar, (float*)d_out);
}

// Round 4
// 274.974 us; speedup vs baseline: 2.8275x; 1.5114x over previous
//
#include <hip/hip_runtime.h>
#include <cstdint>
#include <cstddef>

#define T_ 4
#define N_ 512
#define C_ 256
#define V_ 25
#define H_ 8

typedef _Float16 half8_t __attribute__((ext_vector_type(8)));
typedef float f32x16 __attribute__((ext_vector_type(16)));

__device__ __forceinline__ f32x16 mfma16(half8_t a, half8_t b, f32x16 c) {
  return __builtin_amdgcn_mfma_f32_32x32x16_f16(a, b, c, 0, 0, 0);
}

// ---- KW: pre-swizzled, BN-scaled, fp16-split weights ----
// Wstg layout (halves): i = ((((c*4+p)*4+s)*2+m)*4+rt)*512 + lane*8 + j
//   chunk c: 0..5 = qkv (br=c>>1, rows (c&1)*128+..), 6..7 = proj
//   kt = p*4+s ; row = rt*32+(lane&31) ; k = kt*16+(lane>>5)*8+j ; m: 0=hi,1=lo
__global__ void kw_stage(const float* __restrict__ wq, const float* __restrict__ wk,
                         const float* __restrict__ wv, const float* __restrict__ wp,
                         const float* __restrict__ qg, const float* __restrict__ qvar,
                         const float* __restrict__ kg, const float* __restrict__ kvar,
                         const float* __restrict__ vg, const float* __restrict__ vvar,
                         const float* __restrict__ pg, const float* __restrict__ pvar,
                         _Float16* __restrict__ Wstg) {
  int i = blockIdx.x * 512 + threadIdx.x;          // < 524288
  int j = i & 7, lane = (i >> 3) & 63, rt = (i >> 9) & 3, m = (i >> 11) & 1;
  int s = (i >> 12) & 3, p = (i >> 14) & 3, c = i >> 16;
  int kt = p * 4 + s;
  int row = rt * 32 + (lane & 31);
  int k = kt * 16 + (lane >> 5) * 8 + j;
  const float *w, *g, *va;
  int grow;
  if (c < 6) {
    int br = c >> 1;
    w = br == 0 ? wq : br == 1 ? wk : wv;
    g = br == 0 ? qg : br == 1 ? kg : vg;
    va = br == 0 ? qvar : br == 1 ? kvar : vvar;
    grow = (c & 1) * 128 + row;
  } else {
    w = wp; g = pg; va = pvar;
    grow = (c - 6) * 128 + row;
  }
  float sc = g[grow] / sqrtf(va[grow] + 1e-5f);
  float wv_ = w[grow * 256 + k] * sc;
  _Float16 hi = (_Float16)wv_;
  Wstg[i] = (m == 0) ? hi : (_Float16)(wv_ - (float)hi);
}

// Stage one 32KB phase block (4 kt) of Wstg into an LDS A-buffer, lane-linear.
#define STAGE_A(gidx, bufsel)                                                     \
  do {                                                                            \
    const _Float16* sp_ = Wstg + (size_t)(gidx) * 16384 + tid * 8;                \
    char* dp_ = Abuf + (bufsel) * 32768 + tid * 16;                               \
    __builtin_amdgcn_global_load_lds((const uint32_t*)(sp_),          (uint32_t*)(dp_),          16, 0, 0); \
    __builtin_amdgcn_global_load_lds((const uint32_t*)(sp_ + 4096),   (uint32_t*)(dp_ + 8192),   16, 0, 0); \
    __builtin_amdgcn_global_load_lds((const uint32_t*)(sp_ + 8192),   (uint32_t*)(dp_ + 16384),  16, 0, 0); \
    __builtin_amdgcn_global_load_lds((const uint32_t*)(sp_ + 12288),  (uint32_t*)(dp_ + 24576),  16, 0, 0); \
  } while (0)

// ---- K1: fused qkv conv (BN-folded, fp16-split MFMA) + LIF -> spike bitmasks ----
// block = n, 8 waves = 2 rg x 4 cg; wave tile 64 rows x 32 cols; col = t*25+v (<100)
__launch_bounds__(512, 1)
__global__ void k1_mfma(const float* __restrict__ x, const _Float16* __restrict__ Wstg,
                        const float* __restrict__ qg, const float* __restrict__ qb,
                        const float* __restrict__ qm, const float* __restrict__ qvar,
                        const float* __restrict__ kg, const float* __restrict__ kb,
                        const float* __restrict__ km, const float* __restrict__ kvar,
                        const float* __restrict__ vg, const float* __restrict__ vb,
                        const float* __restrict__ vm, const float* __restrict__ vvar,
                        uint32_t* __restrict__ masks) {
  __shared__ __align__(16) char LDSb[102400 + 25856 + 512];
  float* Xf = (float*)LDSb;            // [4][256][25] f32, prologue only
  char* Abuf = LDSb;                   // 2 x 32KB double buffer (aliases Xf)
  float* Ms = (float*)(LDSb + 102400); // [64][101]
  float* bic = (float*)(LDSb + 102400 + 25856);

  const int n = blockIdx.x, tid = threadIdx.x;
  const int lane = tid & 63, wid = tid >> 6;
  const int rg = wid >> 2, cg = wid & 3;
  const int lr = lane & 31, lkg = lane >> 5;

  // stage x[:, n, :, :] into Xf (linear, coalesced DMA)
  for (int t = 0; t < 4; ++t) {
    const float* sp = x + (size_t)(t * N_ + n) * 6400;
    float* dp = Xf + t * 6400;
    for (int i = tid; i < 1600; i += 512)
      __builtin_amdgcn_global_load_lds((const uint32_t*)(sp + i * 4), (uint32_t*)(dp + i * 4), 16, 0, 0);
  }
  __syncthreads();

  // build B fragments in registers: fp16 hi/lo split of x, col = cg*32+lr
  half8_t Bf0[16], Bf1[16];
  {
    int col = cg * 32 + lr;
    bool valid = col < 100;
    int tq = valid ? col / 25 : 0;
    int v = valid ? col - tq * 25 : 0;
    const float* xb = Xf + tq * 6400 + v;
#pragma unroll
    for (int kt = 0; kt < 16; ++kt) {
#pragma unroll
      for (int jj = 0; jj < 8; ++jj) {
        int k = kt * 16 + lkg * 8 + jj;
        float f = xb[k * 25];
        f = valid ? f : 0.0f;
        _Float16 hi = (_Float16)f;
        Bf0[kt][jj] = hi;
        Bf1[kt][jj] = (_Float16)(f - (float)hi);
      }
    }
  }
  __syncthreads();          // all Xf reads done; Abuf region free
  STAGE_A(0, 0);            // chunk 0, phase 0

  for (int c = 0; c < 6; ++c) {
    if (tid < 128) {
      int ch = (c & 1) * 128 + tid;
      const int br = c >> 1;
      const float* g  = br == 0 ? qg : br == 1 ? kg : vg;
      const float* be = br == 0 ? qb : br == 1 ? kb : vb;
      const float* mu = br == 0 ? qm : br == 1 ? km : vm;
      const float* va = br == 0 ? qvar : br == 1 ? kvar : vvar;
      float sc = g[ch] / sqrtf(va[ch] + 1e-5f);
      bic[tid] = be[ch] - mu[ch] * sc;
    }
    f32x16 acc0 = {}, acc1 = {};
#pragma unroll
    for (int p = 0; p < 4; ++p) {
      __syncthreads();      // phase p data ready (vmcnt drained by barrier)
      int gnext = c * 4 + p + 1;
      if (gnext < 24) STAGE_A(gnext, (p + 1) & 1);
#pragma unroll
      for (int s = 0; s < 4; ++s) {
        const char* kb = Abuf + (p & 1) * 32768 + s * 8192;
        half8_t A00 = *(const half8_t*)(kb + 0    + 2 * rg * 1024 + lane * 16);
        half8_t A01 = *(const half8_t*)(kb + 0    + (2 * rg + 1) * 1024 + lane * 16);
        half8_t A10 = *(const half8_t*)(kb + 4096 + 2 * rg * 1024 + lane * 16);
        half8_t A11 = *(const half8_t*)(kb + 4096 + (2 * rg + 1) * 1024 + lane * 16);
        int kt = p * 4 + s;
        __builtin_amdgcn_s_setprio(1);
        acc0 = mfma16(A00, Bf0[kt], acc0);
        acc1 = mfma16(A01, Bf0[kt], acc1);
        acc0 = mfma16(A00, Bf1[kt], acc0);
        acc1 = mfma16(A01, Bf1[kt], acc1);
        acc0 = mfma16(A10, Bf0[kt], acc0);
        acc1 = mfma16(A11, Bf0[kt], acc1);
        __builtin_amdgcn_s_setprio(0);
      }
    }

    // epilogue: BN bias add -> Ms, LIF over t, ballot-pack spikes
    const int br = c >> 1;
    for (int ph = 0; ph < 2; ++ph) {
      __syncthreads();
      if (rg == ph) {
        int col = cg * 32 + lr;
        if (col < 100) {
#pragma unroll
          for (int rr = 0; rr < 16; ++rr) {
            int rowc = (rr & 3) + 8 * (rr >> 2) + 4 * lkg;
            Ms[rowc * 101 + col] = acc0[rr] + bic[ph * 64 + rowc];
            Ms[(32 + rowc) * 101 + col] = acc1[rr] + bic[ph * 64 + 32 + rowc];
          }
        }
      }
      __syncthreads();
      const int d = lane & 31, sub = lane >> 5;
      for (int it = 0; it < 4; ++it) {
        int ti = it * 16 + wid * 2 + sub;
        bool valid = ti < 50;
        int hl = valid ? ti / 25 : 0;
        int v = valid ? ti - hl * 25 : 0;
        int row = hl * 32 + d;
        float st = 0.0f;
#pragma unroll
        for (int t = 0; t < 4; ++t) {
          float cu = Ms[row * 101 + t * 25 + v];
          st += (cu - st) * 0.5f;
          bool sbit = valid && (st >= 1.0f);
          if (st >= 1.0f) st = 0.0f;
          unsigned long long b = __ballot(sbit);
          if (valid && (lane == 0 || lane == 32)) {
            uint32_t wd = (lane == 0) ? (uint32_t)b : (uint32_t)(b >> 32);
            int hg = (c & 1) * 4 + ph * 2 + hl;
            masks[((((size_t)t * N_ + n) * 3 + br) * H_ + hg) * V_ + v] = wd;
          }
        }
      }
    }
  }
}

// ---- K2: binary attention (popcount) + attn_lif -> mask2 (exact dyadic) ----
__launch_bounds__(64)
__global__ void k2_attn(const uint32_t* __restrict__ masks, uint32_t* __restrict__ mask2) {
  __shared__ uint32_t qs[T_][V_], ks_[T_][V_], vs[T_][V_];
  const int n = blockIdx.x >> 3;
  const int h = blockIdx.x & 7;
  const int l = threadIdx.x;
  for (int i = l; i < T_ * 3 * V_; i += 64) {
    int t = i / (3 * V_);
    int r = i - t * (3 * V_);
    int br = r / V_;
    int v = r - br * V_;
    uint32_t w = masks[(((size_t)t * N_ + n) * 3 + br) * (H_ * V_) + h * V_ + v];
    if (br == 0) qs[t][v] = w;
    else if (br == 1) ks_[t][v] = w;
    else vs[t][v] = w;
  }
  __syncthreads();
  const int hi = l >> 5, d = l & 31;
  for (int vv = 0; vv < 13; ++vv) {
    int v = vv * 2 + hi;
    bool valid = (v < V_);
    int vc = valid ? v : 0;
    float st = 0.0f;
#pragma unroll
    for (int t = 0; t < 4; ++t) {
      int y = 0;
      uint32_t qmw = qs[t][vc];
#pragma unroll
      for (int w = 0; w < V_; ++w) {
        int a = __popc(qmw & ks_[t][w]);
        y += a * (int)((vs[t][w] >> d) & 1u);
      }
      float yf = 0.125f * (float)y;
      st += (yf - st) * 0.5f;
      bool s = valid && (st >= 0.5f);
      if (st >= 0.5f) st = 0.0f;
      unsigned long long b = __ballot(s);
      if (valid && (l == 0 || l == 32)) {
        uint32_t wd = (l == 0) ? (uint32_t)b : (uint32_t)(b >> 32);
        mask2[(((size_t)t * N_ + n) * V_ + v) * H_ + h] = wd;
      }
    }
  }
}

// ---- K3: proj conv (binary B, fp16-split W MFMA) + bias/BN + LIF + residual ----
__launch_bounds__(512, 1)
__global__ void k3_mfma(const float* __restrict__ x, const _Float16* __restrict__ Wstg,
                        const uint32_t* __restrict__ mask2, const float* __restrict__ bp,
                        const float* __restrict__ pg, const float* __restrict__ pb,
                        const float* __restrict__ pm, const float* __restrict__ pvar,
                        float* __restrict__ out) {
  __shared__ __align__(16) char LDSb[65536 + 25856 + 512 + 3200];
  char* Abuf = LDSb;
  float* Ms = (float*)(LDSb + 65536);
  float* bic = (float*)(LDSb + 65536 + 25856);
  uint32_t* m2s = (uint32_t*)(LDSb + 65536 + 25856 + 512);

  const int n = blockIdx.x, tid = threadIdx.x;
  const int lane = tid & 63, wid = tid >> 6;
  const int rg = wid >> 2, cg = wid & 3;
  const int lr = lane & 31, lkg = lane >> 5;

  for (int i = tid; i < 800; i += 512) {
    int t = i / 200, r = i - t * 200;
    m2s[i] = mask2[(size_t)(t * N_ + n) * 200 + r];
  }
  __syncthreads();

  half8_t Bf[16];
  {
    int col = cg * 32 + lr;
    bool valid = col < 100;
    int tq = valid ? col / 25 : 0;
    int v = valid ? col - tq * 25 : 0;
#pragma unroll
    for (int kt = 0; kt < 16; ++kt) {
#pragma unroll
      for (int jj = 0; jj < 8; ++jj) {
        int k = kt * 16 + lkg * 8 + jj;
        uint32_t bit = (m2s[tq * 200 + v * 8 + (k >> 5)] >> (k & 31)) & 1u;
        Bf[kt][jj] = (valid && bit) ? (_Float16)1.0f : (_Float16)0.0f;
      }
    }
  }
  STAGE_A(24, 0);  // chunk 6, phase 0

  for (int c = 0; c < 2; ++c) {
    if (tid < 128) {
      int ch = c * 128 + tid;
      float sc = pg[ch] / sqrtf(pvar[ch] + 1e-5f);
      bic[tid] = fmaf(bp[ch] - pm[ch], sc, pb[ch]);
    }
    f32x16 acc0 = {}, acc1 = {};
#pragma unroll
    for (int p = 0; p < 4; ++p) {
      __syncthreads();
      int gnext = (6 + c) * 4 + p + 1;
      if (gnext < 32) STAGE_A(gnext, (p + 1) & 1);
#pragma unroll
      for (int s = 0; s < 4; ++s) {
        const char* kb = Abuf + (p & 1) * 32768 + s * 8192;
        half8_t A00 = *(const half8_t*)(kb + 0    + 2 * rg * 1024 + lane * 16);
        half8_t A01 = *(const half8_t*)(kb + 0    + (2 * rg + 1) * 1024 + lane * 16);
        half8_t A10 = *(const half8_t*)(kb + 4096 + 2 * rg * 1024 + lane * 16);
        half8_t A11 = *(const half8_t*)(kb + 4096 + (2 * rg + 1) * 1024 + lane * 16);
        int kt = p * 4 + s;
        __builtin_amdgcn_s_setprio(1);
        acc0 = mfma16(A00, Bf[kt], acc0);
        acc1 = mfma16(A01, Bf[kt], acc1);
        acc0 = mfma16(A10, Bf[kt], acc0);
        acc1 = mfma16(A11, Bf[kt], acc1);
        __builtin_amdgcn_s_setprio(0);
      }
    }

    for (int ph = 0; ph < 2; ++ph) {
      __syncthreads();
      if (rg == ph) {
        int col = cg * 32 + lr;
        if (col < 100) {
#pragma unroll
          for (int rr = 0; rr < 16; ++rr) {
            int rowc = (rr & 3) + 8 * (rr >> 2) + 4 * lkg;
            Ms[rowc * 101 + col] = acc0[rr] + bic[ph * 64 + rowc];
            Ms[(32 + rowc) * 101 + col] = acc1[rr] + bic[ph * 64 + 32 + rowc];
          }
        }
      }
      __syncthreads();
      const int d = lane & 31, sub = lane >> 5;
      for (int it = 0; it < 4; ++it) {
        int ti = it * 16 + wid * 2 + sub;
        if (ti < 50) {
          int hl = ti / 25, v = ti - hl * 25;
          int row = hl * 32 + d;
          float st = 0.0f;
#pragma unroll
          for (int t = 0; t < 4; ++t) {
            float cu = Ms[row * 101 + t * 25 + v];
            st += (cu - st) * 0.5f;
            float s = (st >= 1.0f) ? 1.0f : 0.0f;
            if (st >= 1.0f) st = 0.0f;
            Ms[row * 101 + t * 25 + v] = s;
          }
        }
      }
      __syncthreads();
      for (int ii = tid; ii < 6400; ii += 512) {
        int t = ii / 1600, r2 = ii - t * 1600;
        int cl = r2 / 25, v = r2 - cl * 25;
        size_t go = (size_t)(t * N_ + n) * 6400 + (size_t)(c * 128 + ph * 64 + cl) * 25 + v;
        out[go] = Ms[cl * 101 + t * 25 + v] + x[go];
      }
    }
  }
}

extern "C" void kernel_launch(void* const* d_in, const int* in_sizes, int n_in,
                              void* d_out, int out_size, void* d_ws, size_t ws_size,
                              hipStream_t stream) {
  const float* x    = (const float*)d_in[0];
  const float* wq   = (const float*)d_in[1];
  const float* wk   = (const float*)d_in[2];
  const float* wv   = (const float*)d_in[3];
  const float* wp   = (const float*)d_in[4];
  const float* bp   = (const float*)d_in[5];
  const float* qg   = (const float*)d_in[6];
  const float* qb   = (const float*)d_in[7];
  const float* qm   = (const float*)d_in[8];
  const float* qvar = (const float*)d_in[9];
  const float* kg   = (const float*)d_in[10];
  const float* kb   = (const float*)d_in[11];
  const float* km   = (const float*)d_in[12];
  const float* kvar = (const float*)d_in[13];
  const float* vg   = (const float*)d_in[14];
  const float* vb   = (const float*)d_in[15];
  const float* vm   = (const float*)d_in[16];
  const float* vvar = (const float*)d_in[17];
  const float* pg   = (const float*)d_in[18];
  const float* pb   = (const float*)d_in[19];
  const float* pm   = (const float*)d_in[20];
  const float* pvar = (const float*)d_in[21];

  _Float16* Wstg  = (_Float16*)d_ws;               // 1 MB pre-swizzled weights
  uint32_t* masks = (uint32_t*)d_ws + 262144;      // 4*512*3*8*25
  uint32_t* mask2 = masks + 1228800;               // 4*512*25*8

  kw_stage<<<1024, 512, 0, stream>>>(wq, wk, wv, wp, qg, qvar, kg, kvar,
                                     vg, vvar, pg, pvar, Wstg);
  k1_mfma<<<512, 512, 0, stream>>>(x, Wstg, qg, qb, qm, qvar, kg, kb, km, kvar,
                                   vg, vb, vm, vvar, masks);
  k2_attn<<<4096, 64, 0, stream>>>(masks, mask2);
  k3_mfma<<<512, 512, 0, stream>>>(x, Wstg, mask2, bp, pg, pb, pm, pvar, (float*)d_out);
}